// Round 8
// baseline (141.084 us; speedup 1.0000x reference)
//
#include <hip/hip_runtime.h>

// ---------------------------------------------------------------------------
// CVX_Reasoning_Engine — Round 8: 8 waves/block (512 thr), 32 rows.
//   R7 was L2-latency-bound on the B-fragment chain at 2 waves/SIMD.
//   Same traffic, same LDS, but n-slices split across 8 waves -> per-wave
//   load chain halves and waves/SIMD doubles to 4. L4 = 2m x 4n waves.
// ---------------------------------------------------------------------------

#define MROWS 16384

typedef __attribute__((ext_vector_type(8))) short bf16x8;   // 8 bf16 = 4 VGPRs
typedef __attribute__((ext_vector_type(4))) float floatx4;

__device__ __forceinline__ unsigned short f2bf(float x) {
    union { float f; unsigned u; } c; c.f = x;
    unsigned r = c.u + 0x7fffu + ((c.u >> 16) & 1u);   // RNE
    return (unsigned short)(r >> 16);
}
__device__ __forceinline__ float bf2f(unsigned short b) {
    union { unsigned u; float f; } c; c.u = ((unsigned)b) << 16;
    return c.f;
}

// ---- pack W (KxN fp32) -> fragment-ordered bf16 ----------------------------
// T[((ntile*KS + ks)*64 + lane)*8 + e] = W[k][n],  n = ntile*16 + (lane&15),
// k = ks*32 + (lane>>4)*8 + e.  Reads coalesced (idx = k*N + n, n fastest).
__global__ __launch_bounds__(256) void pack_wt(
    const float* __restrict__ W1, unsigned short* __restrict__ T1,
    const float* __restrict__ W2, unsigned short* __restrict__ T2,
    const float* __restrict__ W3, unsigned short* __restrict__ T3,
    const float* __restrict__ W4, unsigned short* __restrict__ T4)
{
    const float* W; unsigned short* T; int Kreal, KS, nshift;
    switch (blockIdx.y) {
        case 0:  W = W1; T = T1; Kreal = 516; KS = 17; nshift = 9; break;
        case 1:  W = W2; T = T2; Kreal = 512; KS = 16; nshift = 8; break;
        case 2:  W = W3; T = T3; Kreal = 256; KS = 8;  nshift = 7; break;
        default: W = W4; T = T4; Kreal = 128; KS = 4;  nshift = 6; break;
    }
    const int N = 1 << nshift;
    const int idx = blockIdx.x * 256 + threadIdx.x;   // k*N + n over padded K
    if (idx >= N * KS * 32) return;
    const int k = idx >> nshift;
    const int n = idx & (N - 1);
    const unsigned short v = (k < Kreal) ? f2bf(W[idx]) : (unsigned short)0;
    const int ntile = n >> 4, m_l = n & 15;
    const int ks = k >> 5, quad = (k >> 3) & 3, e = k & 7;
    T[(size_t)(((ntile * KS + ks) * 64) + quad * 16 + m_l) * 8 + e] = v;
}

// ---- LDS layout (ushort element offsets) — identical to R7 ------------------
#define OFF_ZS   0
#define LD_ZS    552
#define OFF_H1   17664
#define LD_H1    520
#define OFF_H2   0
#define LD_H2    264
#define OFF_H3   17664
#define LD_H3    136
#define OFF_H4   8448
#define LD_H4    72
#define LDS_TOT  34304

// generic MFMA layer: C[32xN] = lrelu(A[32xK] @ W^T + bias), barrier-free.
// Wt fragment-ordered; 8 waves split N; wave tile 32 x (NF*16).
template<int NF, int KSTEPS>
__device__ __forceinline__ void layer_gemm(
    unsigned short* lds, int offA, int lda, int offC, int ldc,
    const unsigned short* __restrict__ Wt,
    const float* __restrict__ bias, int wid, int lane)
{
    const int m_l = lane & 15, quad = lane >> 4;
    const unsigned short* __restrict__ Wl =
        Wt + ((size_t)(wid * NF) * KSTEPS * 64 + lane) * 8;
    floatx4 acc[2][NF];
    #pragma unroll
    for (int i = 0; i < 2; ++i)
        #pragma unroll
        for (int j = 0; j < NF; ++j)
            acc[i][j] = (floatx4){0.f, 0.f, 0.f, 0.f};

    #pragma unroll
    for (int ks = 0; ks < KSTEPS; ++ks) {
        const bf16x8 a0 = *(const bf16x8*)&lds[offA + (m_l     ) * lda + ks*32 + quad*8];
        const bf16x8 a1 = *(const bf16x8*)&lds[offA + (m_l + 16) * lda + ks*32 + quad*8];
        #pragma unroll
        for (int j = 0; j < NF; ++j) {
            const bf16x8 b = *(const bf16x8*)(Wl + (size_t)(j * KSTEPS + ks) * 512);
            acc[0][j] = __builtin_amdgcn_mfma_f32_16x16x32_bf16(a0, b, acc[0][j], 0, 0, 0);
            acc[1][j] = __builtin_amdgcn_mfma_f32_16x16x32_bf16(a1, b, acc[1][j], 0, 0, 0);
        }
    }
    // epilogue: bias + lrelu -> bf16 LDS. C/D: col=lane&15, row=quad*4+r.
    #pragma unroll
    for (int j = 0; j < NF; ++j) {
        const int col = wid * (NF * 16) + j * 16 + m_l;
        const float bv = bias[col];
        #pragma unroll
        for (int i = 0; i < 2; ++i)
            #pragma unroll
            for (int r = 0; r < 4; ++r) {
                float v = acc[i][j][r] + bv;
                v = v > 0.f ? v : 0.2f * v;
                lds[offC + (i*16 + quad*4 + r) * ldc + col] = f2bf(v);
            }
    }
}

__global__ __launch_bounds__(512, 4) void fused_mlp_qp(
    const float* __restrict__ z, const float* __restrict__ bounds,
    const unsigned short* __restrict__ Wt1, const float* __restrict__ c1,
    const unsigned short* __restrict__ Wt2, const float* __restrict__ c2,
    const unsigned short* __restrict__ Wt3, const float* __restrict__ c3,
    const unsigned short* __restrict__ Wt4, const float* __restrict__ c4,
    const float* __restrict__ W5, const float* __restrict__ c5,
    float* __restrict__ out)
{
    __shared__ unsigned short lds[LDS_TOT];
    const int tid  = threadIdx.x;
    const int wid  = tid >> 6, lane = tid & 63;    // wid 0..7
    const int m_l  = lane & 15, quad = lane >> 4;
    const int bm   = blockIdx.x * 32;

    const float4 bnd = *(const float4*)bounds;

    // ---- stage ALL of z for this block (one latency, then barrier) ---------
    {
        const float4* __restrict__ zf = (const float4*)(z + (size_t)bm * 512);
        #pragma unroll
        for (int i = 0; i < 8; ++i) {
            const int f   = i * 512 + tid;          // float4 idx in 32x128
            const int row = f >> 7, c4 = f & 127;
            const float4 v = zf[f];
            unsigned short t4[4] = {f2bf(v.x), f2bf(v.y), f2bf(v.z), f2bf(v.w)};
            *(uint2*)&lds[OFF_ZS + row * LD_ZS + c4 * 4] = *(uint2*)t4;
        }
        // tail cols 512..551: bounds then zeros (5 x 8-ushort chunks per row)
        if (tid < 160) {
            const int row = tid / 5, j = tid % 5;
            unsigned short t8[8] = {0,0,0,0,0,0,0,0};
            if (j == 0) { t8[0] = f2bf(bnd.x); t8[1] = f2bf(bnd.y);
                          t8[2] = f2bf(bnd.z); t8[3] = f2bf(bnd.w); }
            *(uint4*)&lds[OFF_ZS + row * LD_ZS + 512 + j * 8] = *(uint4*)t8;
        }
    }
    __syncthreads();

    // ---- MFMA layers (barrier-free inside) ---------------------------------
    layer_gemm<4,17>(lds, OFF_ZS, LD_ZS, OFF_H1, LD_H1, Wt1, c1, wid, lane);
    __syncthreads();
    layer_gemm<2,16>(lds, OFF_H1, LD_H1, OFF_H2, LD_H2, Wt2, c2, wid, lane);
    __syncthreads();
    layer_gemm<1,8 >(lds, OFF_H2, LD_H2, OFF_H3, LD_H3, Wt3, c3, wid, lane);
    __syncthreads();
    // L4: 128 -> 64, 2m x 4n waves, one 16x16 tile each
    {
        const int wm4 = wid >> 2, wn4 = wid & 3;
        const unsigned short* __restrict__ Wl4 =
            Wt4 + ((size_t)(wn4 * 4) * 64 + lane) * 8;     // ntile=wn4, KS=4
        floatx4 acc4 = (floatx4){0.f, 0.f, 0.f, 0.f};
        #pragma unroll
        for (int ks = 0; ks < 4; ++ks) {
            const bf16x8 a = *(const bf16x8*)&lds[OFF_H3 + (wm4*16 + m_l) * LD_H3 + ks*32 + quad*8];
            const bf16x8 b = *(const bf16x8*)(Wl4 + (size_t)ks * 512);
            acc4 = __builtin_amdgcn_mfma_f32_16x16x32_bf16(a, b, acc4, 0, 0, 0);
        }
        const int col = wn4 * 16 + m_l;
        const float bv = c4[col];
        #pragma unroll
        for (int r = 0; r < 4; ++r) {
            float v = acc4[r] + bv;
            v = v > 0.f ? v : 0.2f * v;
            lds[OFF_H4 + (wm4*16 + quad*4 + r) * LD_H4 + col] = f2bf(v);
        }
    }
    __syncthreads();

    // ---------------- Layer 5 (64->256 fp32) + QP ---------------------------
    const float4 cc = ((const float4*)c5)[lane];
    float ax[4], ay[4], aw[4], ah[4];
    #pragma unroll
    for (int r = 0; r < 4; ++r) { ax[r] = cc.x; ay[r] = cc.y; aw[r] = cc.z; ah[r] = cc.w; }
    const float4* __restrict__ W5v = (const float4*)W5;   // [k][64 objs]
    const int rbase = wid * 4;                            // 8 waves x 4 rows

    #pragma unroll 2
    for (int k4 = 0; k4 < 64; k4 += 4) {
        unsigned short hs[4][4];
        #pragma unroll
        for (int r = 0; r < 4; ++r) {
            const ushort4 t = *(const ushort4*)&lds[OFF_H4 + (rbase + r) * LD_H4 + k4];
            hs[r][0] = t.x; hs[r][1] = t.y; hs[r][2] = t.z; hs[r][3] = t.w;
        }
        #pragma unroll
        for (int kk = 0; kk < 4; ++kk) {
            const float4 w = W5v[(size_t)(k4 + kk) * 64 + lane];
            #pragma unroll
            for (int r = 0; r < 4; ++r) {
                const float h = bf2f(hs[r][kk]);
                ax[r] = fmaf(h, w.x, ax[r]);
                ay[r] = fmaf(h, w.y, ay[r]);
                aw[r] = fmaf(h, w.z, aw[r]);
                ah[r] = fmaf(h, w.w, ah[r]);
            }
        }
    }

    const float b0 = bnd.x, b1 = bnd.y, b2 = bnd.z, b3 = bnd.w;
    #pragma unroll
    for (int r = 0; r < 4; ++r) {
        float xs, wo, ys, ho;
        {
            const float px = ax[r], pw = aw[r];
            const float x0 = fmaxf(px, b0);
            const float g0 = fmaxf(pw, 1.0f);
            const float t  = 0.5f * (b2 - px - pw);
            const float xl = fminf(fmaxf(px + t, b0), b2 - 1.0f);
            const bool over = (x0 + g0) > b2;
            const float x = over ? xl : x0;
            const float g = over ? (b2 - xl) : g0;
            xs = x; wo = x + g;
        }
        {
            const float py = ay[r], ph = ah[r];
            const float x0 = fmaxf(py, b1);
            const float g0 = fmaxf(ph, 1.0f);
            const float t  = 0.5f * (b3 - py - ph);
            const float xl = fminf(fmaxf(py + t, b1), b3 - 1.0f);
            const bool over = (x0 + g0) > b3;
            const float x = over ? xl : x0;
            const float g = over ? (b3 - xl) : g0;
            ys = x; ho = x + g;
        }
        float4 o; o.x = xs; o.y = ys; o.z = wo; o.w = ho;
        ((float4*)out)[(size_t)(bm + rbase + r) * 64 + lane] = o;
    }
}

extern "C" void kernel_launch(void* const* d_in, const int* in_sizes, int n_in,
                              void* d_out, int out_size, void* d_ws, size_t ws_size,
                              hipStream_t stream) {
    const float* z      = (const float*)d_in[0];
    const float* bounds = (const float*)d_in[1];
    const float* W1 = (const float*)d_in[2];
    const float* c1 = (const float*)d_in[3];
    const float* W2 = (const float*)d_in[4];
    const float* c2 = (const float*)d_in[5];
    const float* W3 = (const float*)d_in[6];
    const float* c3 = (const float*)d_in[7];
    const float* W4 = (const float*)d_in[8];
    const float* c4 = (const float*)d_in[9];
    const float* W5 = (const float*)d_in[10];
    const float* c5 = (const float*)d_in[11];
    float* out = (float*)d_out;

    unsigned short* ws  = (unsigned short*)d_ws;
    unsigned short* Wt1 = ws;               // 512x544 = 278528
    unsigned short* Wt2 = Wt1 + 278528;     // 256x512 = 131072
    unsigned short* Wt3 = Wt2 + 131072;     // 128x256 = 32768
    unsigned short* Wt4 = Wt3 + 32768;      //  64x128 =  8192

    pack_wt<<<dim3(1088, 4), 256, 0, stream>>>(W1, Wt1, W2, Wt2, W3, Wt3, W4, Wt4);
    fused_mlp_qp<<<dim3(MROWS / 32), 512, 0, stream>>>(
        z, bounds, Wt1, c1, Wt2, c2, Wt3, c3, Wt4, c4, W5, c5, out);
}